// Round 1
// baseline (475.055 us; speedup 1.0000x reference)
//
#include <hip/hip_runtime.h>

// SegmentTree prefix-sum sampling, 2^24 leaves, 65536 queries.
// Fanout-16 tree: levels 16, 256, 4096, 65536, 1048576 nodes + root (~4.5 MB ws).
// All stored values and reconstructed intermediates use the exact pairwise
// association of the reference build (((a+b)+(c+d))+((e+f)+(g+h))), so the
// binary descent is bit-identical to the fp32 jax reference. No fast-math.
// fp32 add is commutative, so shfl-butterfly partner sums (m1+m0 vs m0+m1)
// are bit-identical to the reference association.
//
// R1 changes vs 98.0us baseline:
//  - build: lane-contiguous float4 loads (1KB/wave/instr) + shfl_xor butterfly,
//    replacing 64B-lane-strided dwordx4 loads (64 lines touched per instr).
//  - build_top fused into build via threadfence+atomic last-block pattern
//    (device-scope fence covers cross-XCD L2 non-coherence); its 1-block
//    dispatch is replaced by a 4-byte memset of the completion counter.
//  - descend unchanged (6 dependent 64B loads; latency floor ~2-3us).

#define BATCH_N 65536

// ws offsets in floats (all 64B-aligned)
#define OFF_ROOT 0
#define OFF_A 16       // 16 nodes   (children of root)
#define OFF_B 32       // 256
#define OFF_C 288      // 4096
#define OFF_D 4384     // 65536
#define OFF_E 69920    // 1048576   -> end 1118496 floats (~4.47 MB)
#define OFF_CNT 1118496  // one uint32 completion counter (byte offset 4473984)

__device__ __forceinline__ float sum16_exact(float4 A, float4 B, float4 C, float4 D) {
    float n0 = A.x + A.y, n1 = A.z + A.w, n2 = B.x + B.y, n3 = B.z + B.w;
    float n4 = C.x + C.y, n5 = C.z + C.w, n6 = D.x + D.y, n7 = D.z + D.w;
    float m0 = n0 + n1, m1 = n2 + n3, m2 = n4 + n5, m3 = n6 + n7;
    return (m0 + m1) + (m2 + m3);
}

__device__ __forceinline__ float sum16_exact_s(const float* __restrict__ x) {
    float n0 = x[0] + x[1],  n1 = x[2] + x[3],  n2 = x[4] + x[5],  n3 = x[6] + x[7];
    float n4 = x[8] + x[9],  n5 = x[10] + x[11], n6 = x[12] + x[13], n7 = x[14] + x[15];
    float m0 = n0 + n1, m1 = n2 + n3, m2 = n4 + n5, m3 = n6 + n7;
    return (m0 + m1) + (m2 + m3);
}

// Block-wide fold of 4096 contiguous fp32 values -> 256 (16:1) -> 16 -> 1,
// with the reference's exact pairwise association at every level.
// Loads are lane-contiguous float4 (perfect coalescing); the two lowest
// binary levels per float4 are in-register, the next two via shfl_xor
// butterfly within 4-lane groups (commutative partner sums, bit-exact).
__device__ __forceinline__ void fold4096(const float* __restrict__ src,
                                         float* __restrict__ out256,
                                         float* __restrict__ out16,
                                         float* __restrict__ out1,
                                         float* __restrict__ smE,
                                         float* __restrict__ smD,
                                         const int t) {
    const float4* base = reinterpret_cast<const float4*>(src);
    float4 r0 = base[t];
    float4 r1 = base[256 + t];
    float4 r2 = base[512 + t];
    float4 r3 = base[768 + t];
    // exact level-2 sums: (x+y)+(z+w)
    float m0 = (r0.x + r0.y) + (r0.z + r0.w);
    float m1 = (r1.x + r1.y) + (r1.z + r1.w);
    float m2 = (r2.x + r2.y) + (r2.z + r2.w);
    float m3 = (r3.x + r3.y) + (r3.z + r3.w);
    // butterfly within 4-lane groups: e = (ma+mb)+(mc+md), bit-exact
    float e0 = m0 + __shfl_xor(m0, 1); e0 = e0 + __shfl_xor(e0, 2);
    float e1 = m1 + __shfl_xor(m1, 1); e1 = e1 + __shfl_xor(e1, 2);
    float e2 = m2 + __shfl_xor(m2, 1); e2 = e2 + __shfl_xor(e2, 2);
    float e3 = m3 + __shfl_xor(m3, 1); e3 = e3 + __shfl_xor(e3, 2);
    if ((t & 3) == 0) {
        const int g = t >> 2;   // 0..63
        out256[g]       = e0;
        out256[64 + g]  = e1;
        out256[128 + g] = e2;
        out256[192 + g] = e3;
        smE[g]       = e0;
        smE[64 + g]  = e1;
        smE[128 + g] = e2;
        smE[192 + g] = e3;
    }
    __syncthreads();
    if (t < 16) {
        float d = sum16_exact_s(&smE[16 * t]);
        out16[t] = d;
        smD[t] = d;
    }
    __syncthreads();
    if (t == 0) {
        *out1 = sum16_exact_s(smD);
    }
}

// leaves -> E (2^20), D (2^16), C (2^12); last finished block folds
// C -> B -> A -> root.  grid 4096 x 256.
__global__ __launch_bounds__(256) void build(const float* __restrict__ leaf,
                                             float* __restrict__ ws) {
    __shared__ float smE[256];
    __shared__ float smD[16];
    __shared__ int lastFlag;
    const int t = threadIdx.x;
    const int b = blockIdx.x;

    fold4096(leaf + (size_t)b * 4096,
             ws + OFF_E + (size_t)b * 256,
             ws + OFF_D + (size_t)b * 16,
             ws + OFF_C + b,
             smE, smD, t);

    // last-block-done: make this block's E/D/C stores agent-visible (wbl2),
    // then count completion with a device-scope atomic.
    __threadfence();
    __syncthreads();
    if (t == 0) {
        lastFlag = (atomicAdd(reinterpret_cast<unsigned*>(ws) + OFF_CNT, 1u)
                    == gridDim.x - 1);
    }
    __syncthreads();
    if (lastFlag) {
        __threadfence();   // acquire: invalidate this XCD's L1/L2 before reading C
        fold4096(ws + OFF_C,
                 ws + OFF_B,
                 ws + OFF_A,
                 ws + OFF_ROOT,
                 smE, smD, t);
    }
}

// One fanout-16 step: read 16 children of node p (one 64B line), resolve 4
// bit-exact binary descent levels in-register. picked = chosen child value.
__device__ __forceinline__ void step16(const float* __restrict__ base, int& p, float& v,
                                       float& picked) {
    const float4* q = reinterpret_cast<const float4*>(base + (size_t)p * 16);
    float4 A = q[0], B = q[1], C = q[2], D = q[3];
    // reconstruct intermediate binary levels with the build's exact association
    float n0 = A.x + A.y, n2 = B.x + B.y, n4 = C.x + C.y, n6 = D.x + D.y;
    float m0 = n0 + (A.z + A.w);   // (c0+c1)+(c2+c3)
    float m2 = n4 + (C.z + C.w);   // (c8+c9)+(c10+c11)
    float t0 = m0 + (n2 + (B.z + B.w));  // left child at top binary level

    int ia = t0 < v;  if (ia) v -= t0;
    float mm = ia ? m2 : m0;
    int ib = mm < v;  if (ib) v -= mm;
    float nn = ia ? (ib ? n6 : n4) : (ib ? n2 : n0);
    int ic = nn < v;  if (ic) v -= nn;
    // even child c_{8ia+4ib+2ic} and odd child c_{...+1}
    float se0 = ia ? C.x : A.x, se1 = ia ? C.z : A.z;
    float se2 = ia ? D.x : B.x, se3 = ia ? D.z : B.z;
    float so0 = ia ? C.y : A.y, so1 = ia ? C.w : A.w;
    float so2 = ia ? D.y : B.y, so3 = ia ? D.w : B.w;
    float ce = ic ? (ib ? se3 : se1) : (ib ? se2 : se0);
    float co = ic ? (ib ? so3 : so1) : (ib ? so2 : so0);
    int id = ce < v;  if (id) v -= ce;
    picked = id ? co : ce;
    p = p * 16 + ia * 8 + ib * 4 + ic * 2 + id;
}

// 6-step descent per query.  grid 256 x 256.
__global__ __launch_bounds__(256) void descend(const float* __restrict__ leaf,
                                               const float* __restrict__ frac,
                                               const float* __restrict__ ws,
                                               float* __restrict__ out) {
    const int tid = blockIdx.x * 256 + threadIdx.x;
    float v = frac[tid] * ws[OFF_ROOT];
    int p = 0;
    float picked = 0.0f;
    step16(ws + OFF_A, p, v, picked);
    step16(ws + OFF_B, p, v, picked);
    step16(ws + OFF_C, p, v, picked);
    step16(ws + OFF_D, p, v, picked);
    step16(ws + OFF_E, p, v, picked);
    step16(leaf,       p, v, picked);   // final picked == leaf[index]
    out[tid] = (float)p;                // exact: p < 2^24
    out[BATCH_N + tid] = picked;
}

extern "C" void kernel_launch(void* const* d_in, const int* in_sizes, int n_in,
                              void* d_out, int out_size, void* d_ws, size_t ws_size,
                              hipStream_t stream) {
    const float* leaf = (const float*)d_in[0];
    const float* frac = (const float*)d_in[1];
    float* out = (float*)d_out;
    float* ws  = (float*)d_ws;

    // zero the last-block completion counter (4 bytes; graph-capturable)
    hipMemsetAsync((char*)d_ws + (size_t)OFF_CNT * sizeof(float), 0, 4, stream);
    hipLaunchKernelGGL(build,   dim3(4096), dim3(256), 0, stream, leaf, ws);
    hipLaunchKernelGGL(descend, dim3(256),  dim3(256), 0, stream, leaf, frac, ws, out);
}

// Round 2
// 95.992 us; speedup vs baseline: 4.9489x; 4.9489x over previous
//
#include <hip/hip_runtime.h>

// SegmentTree prefix-sum sampling, 2^24 leaves, 65536 queries.
// Fanout-16 tree. build_lo writes levels E (2^20), D (2^16), C (2^12) to ws;
// the tiny top levels (B=256, A=16, root) are folded REDUNDANTLY in each
// descend block's prologue from C (16 KB, L2-hit) -- this removes the
// 1-block build_top dispatch entirely and lets the first three descent
// levels run out of LDS.
//
// All stored values and reconstructed intermediates use the exact pairwise
// association of the reference build (((a+b)+(c+d))+((e+f)+(g+h))), so the
// binary descent is bit-identical to the fp32 jax reference. No fast-math.
// fp32 add is commutative, so shfl-butterfly partner sums (m1+m0 vs m0+m1)
// are bit-identical to the reference association.
//
// R2 vs R1: the fused last-block pattern is REVERTED -- its per-block
// __threadfence() (buffer_wbl2/inv) serialized at L2: 4096 blocks x ~110ns
// of fence = 450us, VALUBusy 0.33%. No device fences anywhere now.

#define BATCH_N 65536

// ws offsets in floats (all 64B-aligned)
#define OFF_C 288      // 4096 nodes
#define OFF_D 4384     // 65536
#define OFF_E 69920    // 1048576   -> end 1118496 floats (~4.47 MB)

// float4-slot swizzle: node p's 4 slots (4p+j) permuted by j^(p&3).
// Involution; spreads random-p 64B LDS reads over all 8 bank groups.
__device__ __forceinline__ int swz_f4(int s) {
    return (s & ~3) | ((s & 3) ^ ((s >> 2) & 3));
}
// scalar-element address in a swizzled level array
__device__ __forceinline__ int swz_sc(int i) {
    return swz_f4(i >> 2) * 4 + (i & 3);
}

__device__ __forceinline__ float sum16_exact(float4 A, float4 B, float4 C, float4 D) {
    float n0 = A.x + A.y, n1 = A.z + A.w, n2 = B.x + B.y, n3 = B.z + B.w;
    float n4 = C.x + C.y, n5 = C.z + C.w, n6 = D.x + D.y, n7 = D.z + D.w;
    float m0 = n0 + n1, m1 = n2 + n3, m2 = n4 + n5, m3 = n6 + n7;
    return (m0 + m1) + (m2 + m3);
}

__device__ __forceinline__ float sum16_exact_s(const float* __restrict__ x) {
    float n0 = x[0] + x[1],  n1 = x[2] + x[3],  n2 = x[4] + x[5],  n3 = x[6] + x[7];
    float n4 = x[8] + x[9],  n5 = x[10] + x[11], n6 = x[12] + x[13], n7 = x[14] + x[15];
    float m0 = n0 + n1, m1 = n2 + n3, m2 = n4 + n5, m3 = n6 + n7;
    return (m0 + m1) + (m2 + m3);
}

// leaves -> E (2^20), D (2^16), C (2^12).  grid 4096 x 256.
// Lane-contiguous float4 loads (1KB/wave/instr); two lowest binary levels
// in-register, next two via shfl_xor butterfly in 4-lane groups (bit-exact).
__global__ __launch_bounds__(256) void build_lo(const float* __restrict__ leaf,
                                                float* __restrict__ ws) {
    __shared__ float smE[256];
    __shared__ float smD[16];
    const int t = threadIdx.x;
    const int b = blockIdx.x;
    const float4* base = reinterpret_cast<const float4*>(leaf) + (size_t)b * 1024;
    float4 r0 = base[t];
    float4 r1 = base[256 + t];
    float4 r2 = base[512 + t];
    float4 r3 = base[768 + t];
    // exact level-2 sums: (x+y)+(z+w)
    float m0 = (r0.x + r0.y) + (r0.z + r0.w);
    float m1 = (r1.x + r1.y) + (r1.z + r1.w);
    float m2 = (r2.x + r2.y) + (r2.z + r2.w);
    float m3 = (r3.x + r3.y) + (r3.z + r3.w);
    // butterfly within 4-lane groups: e = (ma+mb)+(mc+md), bit-exact
    float e0 = m0 + __shfl_xor(m0, 1); e0 = e0 + __shfl_xor(e0, 2);
    float e1 = m1 + __shfl_xor(m1, 1); e1 = e1 + __shfl_xor(e1, 2);
    float e2 = m2 + __shfl_xor(m2, 1); e2 = e2 + __shfl_xor(e2, 2);
    float e3 = m3 + __shfl_xor(m3, 1); e3 = e3 + __shfl_xor(e3, 2);
    float* outE = ws + OFF_E + (size_t)b * 256;
    if ((t & 3) == 0) {
        const int g = t >> 2;   // 0..63
        outE[g]       = e0;  smE[g]       = e0;
        outE[64 + g]  = e1;  smE[64 + g]  = e1;
        outE[128 + g] = e2;  smE[128 + g] = e2;
        outE[192 + g] = e3;  smE[192 + g] = e3;
    }
    __syncthreads();
    if (t < 16) {
        float d = sum16_exact_s(&smE[16 * t]);
        ws[OFF_D + (size_t)b * 16 + t] = d;
        smD[t] = d;
    }
    __syncthreads();
    if (t == 0) {
        ws[OFF_C + b] = sum16_exact_s(smD);
    }
}

// One fanout-16 step on 16 children already in registers: resolve 4
// bit-exact binary descent levels. picked = chosen child value.
__device__ __forceinline__ void step16_core(float4 A, float4 B, float4 C, float4 D,
                                            int& p, float& v, float& picked) {
    // reconstruct intermediate binary levels with the build's exact association
    float n0 = A.x + A.y, n2 = B.x + B.y, n4 = C.x + C.y, n6 = D.x + D.y;
    float m0 = n0 + (A.z + A.w);   // (c0+c1)+(c2+c3)
    float m2 = n4 + (C.z + C.w);   // (c8+c9)+(c10+c11)
    float t0 = m0 + (n2 + (B.z + B.w));  // left child at top binary level

    int ia = t0 < v;  if (ia) v -= t0;
    float mm = ia ? m2 : m0;
    int ib = mm < v;  if (ib) v -= mm;
    float nn = ia ? (ib ? n6 : n4) : (ib ? n2 : n0);
    int ic = nn < v;  if (ic) v -= nn;
    // even child c_{8ia+4ib+2ic} and odd child c_{...+1}
    float se0 = ia ? C.x : A.x, se1 = ia ? C.z : A.z;
    float se2 = ia ? D.x : B.x, se3 = ia ? D.z : B.z;
    float so0 = ia ? C.y : A.y, so1 = ia ? C.w : A.w;
    float so2 = ia ? D.y : B.y, so3 = ia ? D.w : B.w;
    float ce = ic ? (ib ? se3 : se1) : (ib ? se2 : se0);
    float co = ic ? (ib ? so3 : so1) : (ib ? so2 : so0);
    int id = ce < v;  if (id) v -= ce;
    picked = id ? co : ce;
    p = p * 16 + ia * 8 + ib * 4 + ic * 2 + id;
}

// global-memory step: one 64B line
__device__ __forceinline__ void step16_g(const float* __restrict__ base, int& p,
                                         float& v, float& picked) {
    const float4* q = reinterpret_cast<const float4*>(base) + (size_t)p * 4;
    step16_core(q[0], q[1], q[2], q[3], p, v, picked);
}

// LDS step on a swizzled level array
__device__ __forceinline__ void step16_lds(const float* base, int& p,
                                           float& v, float& picked) {
    const float4* q = reinterpret_cast<const float4*>(base);
    const int b4 = p * 4, px = p & 3;
    float4 A = q[b4 + (0 ^ px)];
    float4 B = q[b4 + (1 ^ px)];
    float4 C = q[b4 + (2 ^ px)];
    float4 D = q[b4 + (3 ^ px)];
    step16_core(A, B, C, D, p, v, picked);
}

// Prologue: load C (4096 floats, swizzled) into LDS, fold C->B->A->root
// (bit-identical in every block). Then 6-step descent per query:
// A,B,C from LDS; D,E,leaf from global.  grid 256 x 256.
__global__ __launch_bounds__(256) void descend(const float* __restrict__ leaf,
                                               const float* __restrict__ frac,
                                               const float* __restrict__ ws,
                                               float* __restrict__ out) {
    __shared__ float sC[4096];
    __shared__ float sB[256];
    __shared__ float sA[16];
    __shared__ float sRoot;
    const int t = threadIdx.x;

    const float4* Cg = reinterpret_cast<const float4*>(ws + OFF_C);
    float4* sC4 = reinterpret_cast<float4*>(sC);
    float4 r0 = Cg[t];
    float4 r1 = Cg[256 + t];
    float4 r2 = Cg[512 + t];
    float4 r3 = Cg[768 + t];
    sC4[swz_f4(t)]       = r0;
    sC4[swz_f4(256 + t)] = r1;
    sC4[swz_f4(512 + t)] = r2;
    sC4[swz_f4(768 + t)] = r3;
    // fold C -> B with the exact association (same butterfly as build)
    float m0 = (r0.x + r0.y) + (r0.z + r0.w);
    float m1 = (r1.x + r1.y) + (r1.z + r1.w);
    float m2 = (r2.x + r2.y) + (r2.z + r2.w);
    float m3 = (r3.x + r3.y) + (r3.z + r3.w);
    float e0 = m0 + __shfl_xor(m0, 1); e0 = e0 + __shfl_xor(e0, 2);
    float e1 = m1 + __shfl_xor(m1, 1); e1 = e1 + __shfl_xor(e1, 2);
    float e2 = m2 + __shfl_xor(m2, 1); e2 = e2 + __shfl_xor(e2, 2);
    float e3 = m3 + __shfl_xor(m3, 1); e3 = e3 + __shfl_xor(e3, 2);
    if ((t & 3) == 0) {
        const int g = t >> 2;   // 0..63
        sB[swz_sc(g)]       = e0;
        sB[swz_sc(64 + g)]  = e1;
        sB[swz_sc(128 + g)] = e2;
        sB[swz_sc(192 + g)] = e3;
    }
    __syncthreads();
    if (t < 16) {
        // gather node t's four float4s from swizzled sB (involution: slot
        // 4t+(j^(t&3)) holds elements B[16t+4j .. 16t+4j+3] in order)
        const float4* sB4 = reinterpret_cast<const float4*>(sB);
        const int b4 = t * 4, px = t & 3;
        float4 A_ = sB4[b4 + (0 ^ px)];
        float4 B_ = sB4[b4 + (1 ^ px)];
        float4 C_ = sB4[b4 + (2 ^ px)];
        float4 D_ = sB4[b4 + (3 ^ px)];
        sA[t] = sum16_exact(A_, B_, C_, D_);
    }
    __syncthreads();
    if (t == 0) {
        sRoot = sum16_exact_s(sA);
    }
    __syncthreads();

    const int tid = blockIdx.x * 256 + t;
    float v = frac[tid] * sRoot;
    int p = 0;
    float picked = 0.0f;
    step16_lds(sA, p, v, picked);       // p=0: swizzle is identity, sA linear
    step16_lds(sB, p, v, picked);
    step16_lds(sC, p, v, picked);
    step16_g(ws + OFF_D, p, v, picked);
    step16_g(ws + OFF_E, p, v, picked);
    step16_g(leaf,       p, v, picked); // final picked == leaf[index]
    out[tid] = (float)p;                // exact: p < 2^24
    out[BATCH_N + tid] = picked;
}

extern "C" void kernel_launch(void* const* d_in, const int* in_sizes, int n_in,
                              void* d_out, int out_size, void* d_ws, size_t ws_size,
                              hipStream_t stream) {
    const float* leaf = (const float*)d_in[0];
    const float* frac = (const float*)d_in[1];
    float* out = (float*)d_out;
    float* ws  = (float*)d_ws;

    hipLaunchKernelGGL(build_lo, dim3(4096), dim3(256), 0, stream, leaf, ws);
    hipLaunchKernelGGL(descend,  dim3(256),  dim3(256), 0, stream, leaf, frac, ws, out);
}